// Round 5
// baseline (164.946 us; speedup 1.0000x reference)
//
#include <hip/hip_runtime.h>
#include <math.h>

#define BATCH 64
#define TLEN 2048
#define DIM 80
#define DQ (DIM / 4)          // 20 float4-quads per row
#define TT 8                  // t-rows per thread strip
#define TCHUNKS (TLEN / TT)   // 256
#define THREADS 256
#define NSTRIPS (BATCH * TCHUNKS * DQ)        // 327680 threads
#define NBLOCKS (NSTRIPS / THREADS)           // 1280

// Smooth-min: K=32; c = K*log2(e)
#define SMIN_C  46.166241308446828f
#define SMIN_RC 0.02166084939249829f   // 1/c

__device__ __forceinline__ void load_row(float r[6], const float* __restrict__ base,
                                         int t, int q) {
    // base -> tgt[b][0][d0]; r[0]=d0-1, r[1..4]=d0..d0+3, r[5]=d0+4
    if (t >= 0 && t < TLEN) {
        const float* p = base + (size_t)t * DIM;
        const float4 v = *(const float4*)p;
        r[0] = (q > 0)      ? p[-1] : 0.f;
        r[1] = v.x; r[2] = v.y; r[3] = v.z; r[4] = v.w;
        r[5] = (q < DQ - 1) ? p[4]  : 0.f;
    } else {
#pragma unroll
        for (int i = 0; i < 6; ++i) r[i] = 0.f;
    }
}

__device__ __forceinline__ float elem_loss(float x, const float* rm, const float* r0,
                                           const float* rp, int e) {
    float v[9];
#pragma unroll
    for (int i = 0; i < 3; ++i) {
        v[0 + i] = fabsf(x - rm[e + i]);
        v[3 + i] = fabsf(x - r0[e + i]);
        v[6 + i] = fabsf(x - rp[e + i]);
    }
    const float center = v[4];
    float m = fminf(fminf(fminf(v[0], v[1]), fminf(v[2], v[3])),
                    fminf(fminf(v[4], v[5]), fminf(v[6], v[7])));
    m = fminf(m, v[8]);
    const float cm = SMIN_C * m;
    float S = 0.f;
#pragma unroll
    for (int s = 0; s < 9; ++s)
        S += __builtin_amdgcn_exp2f(fmaf(-SMIN_C, v[s], cm));   // args <= 0; S in [1,9]
    const float sm = m - __builtin_amdgcn_logf(S) * SMIN_RC;     // logf builtin = log2
    return center + sm;
}

// NOTE: no min-waves arg — __launch_bounds__(256,6) in R4 forced VGPR=40 and
// spilled 32 MB to scratch (WRITE_SIZE 40 KB -> 32 MB), 78 us. Let the
// compiler pick (~R2 regime, no spill, jitter ~30 us).
__global__ __launch_bounds__(THREADS) void jitter_kernel(
    const float* __restrict__ inp, const float* __restrict__ tgt,
    float* __restrict__ ws, float* __restrict__ out)
{
    __shared__ float wsum[THREADS / 64];

    const int n   = blockIdx.x * THREADS + threadIdx.x;
    const int q   = n % DQ;
    const int rem = n / DQ;
    const int tc  = rem % TCHUNKS;
    const int b   = rem / TCHUNKS;
    const int t0  = tc * TT;
    const int d0  = q * 4;

    const float* tgb = tgt + (size_t)b * TLEN * DIM + d0;
    const float* inb = inp + (size_t)b * TLEN * DIM + d0;

    float rm[6], r0[6], rp[6];
    load_row(rm, tgb, t0 - 1, q);
    load_row(r0, tgb, t0,     q);

    float acc = 0.f;
#pragma unroll
    for (int lt = 0; lt < TT; ++lt) {
        load_row(rp, tgb, t0 + lt + 1, q);
        const float4 in4 = *(const float4*)(inb + (size_t)(t0 + lt) * DIM);
        acc += elem_loss(in4.x, rm, r0, rp, 0);
        acc += elem_loss(in4.y, rm, r0, rp, 1);
        acc += elem_loss(in4.z, rm, r0, rp, 2);
        acc += elem_loss(in4.w, rm, r0, rp, 3);
#pragma unroll
        for (int i = 0; i < 6; ++i) { rm[i] = r0[i]; r0[i] = rp[i]; }
    }

    // block reduction -> one partial add per block
#pragma unroll
    for (int off = 32; off > 0; off >>= 1)
        acc += __shfl_down(acc, off, 64);
    const int lane = threadIdx.x & 63, wid = threadIdx.x >> 6;
    if (lane == 0) wsum[wid] = acc;
    __syncthreads();
    if (threadIdx.x == 0) {
        float tot = 0.f;
#pragma unroll
        for (int w = 0; w < THREADS / 64; ++w) tot += wsum[w];
        // device-scope accumulate + last-block finalize (ws[0]=sum, ws_int[1]=count)
        atomicAdd(&ws[0], tot);
        __threadfence();
        int old = atomicAdd((int*)ws + 1, 1);
        if (old == NBLOCKS - 1) {
            __threadfence();
            const float s = atomicAdd(&ws[0], 0.f);  // coherent read of final sum
            out[0] = s * (0.5f / (float)((size_t)BATCH * TLEN * DIM));
        }
    }
}

__global__ void zero_kernel(float* ws) {
    if (threadIdx.x < 2) ws[threadIdx.x] = 0.f;   // zeroes sum (f32) and count (i32)
}

extern "C" void kernel_launch(void* const* d_in, const int* in_sizes, int n_in,
                              void* d_out, int out_size, void* d_ws, size_t ws_size,
                              hipStream_t stream) {
    const float* inp = (const float*)d_in[0];
    const float* tgt = (const float*)d_in[1];
    float* ws  = (float*)d_ws;
    float* out = (float*)d_out;

    zero_kernel<<<1, 64, 0, stream>>>(ws);
    jitter_kernel<<<NBLOCKS, THREADS, 0, stream>>>(inp, tgt, ws, out);
}

// Round 6
// 111.810 us; speedup vs baseline: 1.4752x; 1.4752x over previous
//
#include <hip/hip_runtime.h>
#include <math.h>

#define BATCH 64
#define TLEN 2048
#define DIM 80
#define DQ (DIM / 4)          // 20 float4-quads per row
#define TT 8                  // t-rows per thread strip
#define TCHUNKS (TLEN / TT)   // 256
#define THREADS 256
#define NSTRIPS (BATCH * TCHUNKS * DQ)        // 327680 threads
#define NBLOCKS (NSTRIPS / THREADS)           // 1280

// Smooth-min: K=32; c = K*log2(e)
#define SMIN_C  46.166241308446828f
#define SMIN_RC 0.02166084939249829f   // 1/c

// LESSON (R3/R4/R5): same-cache-line device atomicAdd from all 1280 block
// leaders serializes cross-XCD (~78 us kernel regardless of occupancy/VGPR).
// Per-block plain store + trailing 1-block reduce (R2 structure) is ~45 us
// faster despite the extra launch.

__device__ __forceinline__ void load_row(float r[6], const float* __restrict__ base,
                                         int t, int q) {
    // base -> tgt[b][0][d0]; r[0]=d0-1, r[1..4]=d0..d0+3, r[5]=d0+4
    if (t >= 0 && t < TLEN) {
        const float* p = base + (size_t)t * DIM;
        const float4 v = *(const float4*)p;
        r[0] = (q > 0)      ? p[-1] : 0.f;
        r[1] = v.x; r[2] = v.y; r[3] = v.z; r[4] = v.w;
        r[5] = (q < DQ - 1) ? p[4]  : 0.f;
    } else {
#pragma unroll
        for (int i = 0; i < 6; ++i) r[i] = 0.f;
    }
}

__device__ __forceinline__ float elem_loss(float x, const float* rm, const float* r0,
                                           const float* rp, int e) {
    float v[9];
#pragma unroll
    for (int i = 0; i < 3; ++i) {
        v[0 + i] = fabsf(x - rm[e + i]);
        v[3 + i] = fabsf(x - r0[e + i]);
        v[6 + i] = fabsf(x - rp[e + i]);
    }
    const float center = v[4];
    float m = fminf(fminf(fminf(v[0], v[1]), fminf(v[2], v[3])),
                    fminf(fminf(v[4], v[5]), fminf(v[6], v[7])));
    m = fminf(m, v[8]);
    const float cm = SMIN_C * m;
    float S = 0.f;
#pragma unroll
    for (int s = 0; s < 9; ++s)
        S += __builtin_amdgcn_exp2f(fmaf(-SMIN_C, v[s], cm));   // args <= 0; S in [1,9]
    const float sm = m - __builtin_amdgcn_logf(S) * SMIN_RC;     // logf builtin = log2
    return center + sm;
}

// NOTE: no min-waves arg — __launch_bounds__(256,6) forced VGPR=40 and spilled
// 32 MB to scratch (R4). Compiler-chosen VGPR (~52) is spill-free.
__global__ __launch_bounds__(THREADS) void jitter_kernel(
    const float* __restrict__ inp, const float* __restrict__ tgt,
    float* __restrict__ ws)
{
    __shared__ float wsum[THREADS / 64];

    const int n   = blockIdx.x * THREADS + threadIdx.x;
    const int q   = n % DQ;
    const int rem = n / DQ;
    const int tc  = rem % TCHUNKS;
    const int b   = rem / TCHUNKS;
    const int t0  = tc * TT;
    const int d0  = q * 4;

    const float* tgb = tgt + (size_t)b * TLEN * DIM + d0;
    const float* inb = inp + (size_t)b * TLEN * DIM + d0;

    float rm[6], r0[6], rp[6];
    load_row(rm, tgb, t0 - 1, q);
    load_row(r0, tgb, t0,     q);

    float acc = 0.f;
#pragma unroll
    for (int lt = 0; lt < TT; ++lt) {
        load_row(rp, tgb, t0 + lt + 1, q);
        const float4 in4 = *(const float4*)(inb + (size_t)(t0 + lt) * DIM);
        acc += elem_loss(in4.x, rm, r0, rp, 0);
        acc += elem_loss(in4.y, rm, r0, rp, 1);
        acc += elem_loss(in4.z, rm, r0, rp, 2);
        acc += elem_loss(in4.w, rm, r0, rp, 3);
#pragma unroll
        for (int i = 0; i < 6; ++i) { rm[i] = r0[i]; r0[i] = rp[i]; }
    }

    // block reduction -> one plain store per block (no atomics, no contention)
#pragma unroll
    for (int off = 32; off > 0; off >>= 1)
        acc += __shfl_down(acc, off, 64);
    const int lane = threadIdx.x & 63, wid = threadIdx.x >> 6;
    if (lane == 0) wsum[wid] = acc;
    __syncthreads();
    if (threadIdx.x == 0) {
        float tot = 0.f;
#pragma unroll
        for (int w = 0; w < THREADS / 64; ++w) tot += wsum[w];
        ws[blockIdx.x] = tot;
    }
}

__global__ __launch_bounds__(256) void reduce_kernel(const float* __restrict__ ws,
                                                     float* __restrict__ out) {
    __shared__ float wsum[4];
    float s = 0.f;
    for (int i = threadIdx.x; i < NBLOCKS; i += 256) s += ws[i];
#pragma unroll
    for (int off = 32; off > 0; off >>= 1)
        s += __shfl_down(s, off, 64);
    const int lane = threadIdx.x & 63, wid = threadIdx.x >> 6;
    if (lane == 0) wsum[wid] = s;
    __syncthreads();
    if (threadIdx.x == 0) {
        float tot = wsum[0] + wsum[1] + wsum[2] + wsum[3];
        out[0] = tot * (0.5f / (float)((size_t)BATCH * TLEN * DIM));
    }
}

extern "C" void kernel_launch(void* const* d_in, const int* in_sizes, int n_in,
                              void* d_out, int out_size, void* d_ws, size_t ws_size,
                              hipStream_t stream) {
    const float* inp = (const float*)d_in[0];
    const float* tgt = (const float*)d_in[1];
    float* ws  = (float*)d_ws;
    float* out = (float*)d_out;

    jitter_kernel<<<NBLOCKS, THREADS, 0, stream>>>(inp, tgt, ws);
    reduce_kernel<<<1, 256, 0, stream>>>(ws, out);
}

// Round 7
// 109.523 us; speedup vs baseline: 1.5060x; 1.0209x over previous
//
#include <hip/hip_runtime.h>
#include <math.h>

#define BATCH 64
#define TLEN 2048
#define DIM 80
#define DQ (DIM / 4)          // 20 float4-quads per row
#define TT 4                  // t-rows per thread strip (R6 used 8; 4 doubles TLP)
#define TCHUNKS (TLEN / TT)   // 512
#define THREADS 256
#define NSTRIPS (BATCH * TCHUNKS * DQ)        // 655360 threads
#define NBLOCKS (NSTRIPS / THREADS)           // 2560 -> 10 blocks/CU -> 8 waves/SIMD

// Smooth-min: K=32; c = K*log2(e)
#define SMIN_C  46.166241308446828f
#define SMIN_RC 0.02166084939249829f   // 1/c

// LESSON (R3-R5): same-cache-line device atomicAdd from all block leaders
// serializes cross-XCD (~+45 us tail). Plain per-block store + trailing
// 1-block reduce wins. LESSON (R4): forcing waves/EU via __launch_bounds__
// 2nd arg spills to scratch; leave VGPR to the compiler.

__device__ __forceinline__ void load_row(float r[6], const float* __restrict__ base,
                                         int t, int q) {
    // base -> tgt[b][0][d0]; r[0]=d0-1, r[1..4]=d0..d0+3, r[5]=d0+4
    if (t >= 0 && t < TLEN) {
        const float* p = base + (size_t)t * DIM;
        const float4 v = *(const float4*)p;
        r[0] = (q > 0)      ? p[-1] : 0.f;
        r[1] = v.x; r[2] = v.y; r[3] = v.z; r[4] = v.w;
        r[5] = (q < DQ - 1) ? p[4]  : 0.f;
    } else {
#pragma unroll
        for (int i = 0; i < 6; ++i) r[i] = 0.f;
    }
}

__device__ __forceinline__ float elem_loss(float x, const float* rm, const float* r0,
                                           const float* rp, int e) {
    float v[9];
#pragma unroll
    for (int i = 0; i < 3; ++i) {
        v[0 + i] = fabsf(x - rm[e + i]);
        v[3 + i] = fabsf(x - r0[e + i]);
        v[6 + i] = fabsf(x - rp[e + i]);
    }
    const float center = v[4];
    float m = fminf(fminf(fminf(v[0], v[1]), fminf(v[2], v[3])),
                    fminf(fminf(v[4], v[5]), fminf(v[6], v[7])));
    m = fminf(m, v[8]);
    const float cm = SMIN_C * m;
    float S = 0.f;
#pragma unroll
    for (int s = 0; s < 9; ++s)
        S += __builtin_amdgcn_exp2f(fmaf(-SMIN_C, v[s], cm));   // args <= 0; S in [1,9]
    const float sm = m - __builtin_amdgcn_logf(S) * SMIN_RC;     // logf builtin = log2
    return center + sm;
}

__global__ __launch_bounds__(THREADS) void jitter_kernel(
    const float* __restrict__ inp, const float* __restrict__ tgt,
    float* __restrict__ ws)
{
    __shared__ float wsum[THREADS / 64];

    const int n   = blockIdx.x * THREADS + threadIdx.x;
    const int q   = n % DQ;
    const int rem = n / DQ;
    const int tc  = rem % TCHUNKS;
    const int b   = rem / TCHUNKS;
    const int t0  = tc * TT;
    const int d0  = q * 4;

    const float* tgb = tgt + (size_t)b * TLEN * DIM + d0;
    const float* inb = inp + (size_t)b * TLEN * DIM + d0;

    float rm[6], r0[6], rp[6];
    load_row(rm, tgb, t0 - 1, q);
    load_row(r0, tgb, t0,     q);

    float acc = 0.f;
#pragma unroll
    for (int lt = 0; lt < TT; ++lt) {
        load_row(rp, tgb, t0 + lt + 1, q);
        const float4 in4 = *(const float4*)(inb + (size_t)(t0 + lt) * DIM);
        acc += elem_loss(in4.x, rm, r0, rp, 0);
        acc += elem_loss(in4.y, rm, r0, rp, 1);
        acc += elem_loss(in4.z, rm, r0, rp, 2);
        acc += elem_loss(in4.w, rm, r0, rp, 3);
#pragma unroll
        for (int i = 0; i < 6; ++i) { rm[i] = r0[i]; r0[i] = rp[i]; }
    }

    // block reduction -> one plain store per block (no atomics, no contention)
#pragma unroll
    for (int off = 32; off > 0; off >>= 1)
        acc += __shfl_down(acc, off, 64);
    const int lane = threadIdx.x & 63, wid = threadIdx.x >> 6;
    if (lane == 0) wsum[wid] = acc;
    __syncthreads();
    if (threadIdx.x == 0) {
        float tot = 0.f;
#pragma unroll
        for (int w = 0; w < THREADS / 64; ++w) tot += wsum[w];
        ws[blockIdx.x] = tot;
    }
}

__global__ __launch_bounds__(256) void reduce_kernel(const float* __restrict__ ws,
                                                     float* __restrict__ out) {
    __shared__ float wsum[4];
    float s = 0.f;
    for (int i = threadIdx.x; i < NBLOCKS; i += 256) s += ws[i];
#pragma unroll
    for (int off = 32; off > 0; off >>= 1)
        s += __shfl_down(s, off, 64);
    const int lane = threadIdx.x & 63, wid = threadIdx.x >> 6;
    if (lane == 0) wsum[wid] = s;
    __syncthreads();
    if (threadIdx.x == 0) {
        float tot = wsum[0] + wsum[1] + wsum[2] + wsum[3];
        out[0] = tot * (0.5f / (float)((size_t)BATCH * TLEN * DIM));
    }
}

extern "C" void kernel_launch(void* const* d_in, const int* in_sizes, int n_in,
                              void* d_out, int out_size, void* d_ws, size_t ws_size,
                              hipStream_t stream) {
    const float* inp = (const float*)d_in[0];
    const float* tgt = (const float*)d_in[1];
    float* ws  = (float*)d_ws;
    float* out = (float*)d_out;

    jitter_kernel<<<NBLOCKS, THREADS, 0, stream>>>(inp, tgt, ws);
    reduce_kernel<<<1, 256, 0, stream>>>(ws, out);
}